// Round 7
// baseline (293.641 us; speedup 1.0000x reference)
//
#include <hip/hip_runtime.h>

#define BINS 10

typedef float f4 __attribute__((ext_vector_type(4)));

// raw async load: compiler cannot sink it to its use (no implicit waitcnt tie)
#define GLOAD(dst, ptr) \
    asm volatile("global_load_dwordx4 %0, %1, off" : "=v"(dst) : "v"(ptr))

// explicit drain: tied operands order all consumers after this waitcnt
#define WAIT8(N, a0,b0,a1,b1,a2,b2,a3,b3)                                   \
    asm volatile("s_waitcnt vmcnt(" #N ")"                                  \
        : "+v"(a0),"+v"(b0),"+v"(a1),"+v"(b1),                              \
          "+v"(a2),"+v"(b2),"+v"(a3),"+v"(b3))

// Per-element update (identical arithmetic since R3; absmax == 0).
// q = t?p:(1-p) = 1-|p-t| = 1-g; bce = -log(1-g) = -ln2*log2(1-g).
// Accumulate log2(1-g); fold -ln2 in finalize. Counts via ballot->popc (scalar pipe).
__device__ __forceinline__ void elem(float p, float t,
                                     float* __restrict__ sb,
                                     unsigned int* __restrict__ cw)
{
    float g  = fabsf(p - t);
    float l2 = __log2f(1.0f - g);
    int   bi = (int)(g * 10.0f);      // g in (0.01,0.99): bi in [0,9]
#pragma unroll
    for (int b = 0; b < BINS; ++b) {
        bool hit = (bi == b);
        unsigned long long m = __ballot(hit);
        sb[b] += hit ? l2 : 0.0f;
        cw[b] += (unsigned int)__popcll(m);
    }
}

__device__ __forceinline__ void proc4v(const f4 p, const f4 t,
                                       float* __restrict__ sb,
                                       unsigned int* __restrict__ cw)
{
    elem(p.x, t.x, sb, cw); elem(p.y, t.y, sb, cw);
    elem(p.z, t.z, sb, cw); elem(p.w, t.w, sb, cw);
}

__global__ __launch_bounds__(256, 4) void ghm_partial(
    const f4* __restrict__ p4,
    const f4* __restrict__ t4,
    float* __restrict__ gsum,          // [BINS] floats in d_ws
    unsigned int* __restrict__ gcnt,   // [BINS] uints in d_ws
    int n4)
{
    float        sb[BINS];
    unsigned int cw[BINS];
#pragma unroll
    for (int b = 0; b < BINS; ++b) { sb[b] = 0.0f; cw[b] = 0u; }

    const int tid    = threadIdx.x;
    const int start  = blockIdx.x * blockDim.x + tid;
    const int stride = gridDim.x * blockDim.x;
    const int ngrp   = n4 / (4 * stride);   // groups of 4 float4-pairs; 4 at 2048x256
    const size_t s1 = (size_t)stride, s2 = 2 * s1, s3 = 3 * s1, s4 = 4 * s1;

    const f4* pp = p4 + start;
    const f4* tp = t4 + start;

    // bank A and bank B: 8 float4 each (explicit ping-pong, no rotation copies)
    f4 P0, P1, P2, P3, T0, T1, T2, T3;   // bank A
    f4 Q0, Q1, Q2, Q3, U0, U1, U2, U3;   // bank B

    const int g2 = ngrp & ~1;            // even part, software-pipelined
    if (g2 >= 2) {
        // prologue: bank A <- G0
        GLOAD(P0, pp);      GLOAD(T0, tp);
        GLOAD(P1, pp + s1); GLOAD(T1, tp + s1);
        GLOAD(P2, pp + s2); GLOAD(T2, tp + s2);
        GLOAD(P3, pp + s3); GLOAD(T3, tp + s3);
        pp += s4; tp += s4;
        for (int g = 0; g < g2 - 2; g += 2) {
            // bank B <- next group, then consume bank A under vmcnt(8)
            GLOAD(Q0, pp);      GLOAD(U0, tp);
            GLOAD(Q1, pp + s1); GLOAD(U1, tp + s1);
            GLOAD(Q2, pp + s2); GLOAD(U2, tp + s2);
            GLOAD(Q3, pp + s3); GLOAD(U3, tp + s3);
            pp += s4; tp += s4;
            WAIT8(8, P0,T0,P1,T1,P2,T2,P3,T3);
            proc4v(P0,T0,sb,cw); proc4v(P1,T1,sb,cw);
            proc4v(P2,T2,sb,cw); proc4v(P3,T3,sb,cw);
            // bank A <- next group, then consume bank B under vmcnt(8)
            GLOAD(P0, pp);      GLOAD(T0, tp);
            GLOAD(P1, pp + s1); GLOAD(T1, tp + s1);
            GLOAD(P2, pp + s2); GLOAD(T2, tp + s2);
            GLOAD(P3, pp + s3); GLOAD(T3, tp + s3);
            pp += s4; tp += s4;
            WAIT8(8, Q0,U0,Q1,U1,Q2,U2,Q3,U3);
            proc4v(Q0,U0,sb,cw); proc4v(Q1,U1,sb,cw);
            proc4v(Q2,U2,sb,cw); proc4v(Q3,U3,sb,cw);
        }
        // epilogue: bank B <- last group; drain A then B
        GLOAD(Q0, pp);      GLOAD(U0, tp);
        GLOAD(Q1, pp + s1); GLOAD(U1, tp + s1);
        GLOAD(Q2, pp + s2); GLOAD(U2, tp + s2);
        GLOAD(Q3, pp + s3); GLOAD(U3, tp + s3);
        pp += s4; tp += s4;
        WAIT8(8, P0,T0,P1,T1,P2,T2,P3,T3);
        proc4v(P0,T0,sb,cw); proc4v(P1,T1,sb,cw);
        proc4v(P2,T2,sb,cw); proc4v(P3,T3,sb,cw);
        WAIT8(0, Q0,U0,Q1,U1,Q2,U2,Q3,U3);
        proc4v(Q0,U0,sb,cw); proc4v(Q1,U1,sb,cw);
        proc4v(Q2,U2,sb,cw); proc4v(Q3,U3,sb,cw);
    }
    // leftover odd group (never taken at 2048x256 / n4=2^23) — plain C path
    for (int g = g2; g < ngrp; ++g) {
        const f4* pa = p4 + start + (size_t)g * s4;
        const f4* ta = t4 + start + (size_t)g * s4;
        proc4v(pa[0],  ta[0],  sb, cw); proc4v(pa[s1], ta[s1], sb, cw);
        proc4v(pa[s2], ta[s2], sb, cw); proc4v(pa[s3], ta[s3], sb, cw);
    }
    // pair-level tail (n4 not divisible by 4*stride)
    for (int j = start + ngrp * 4 * stride; j < n4; j += stride)
        proc4v(p4[j], t4[j], sb, cw);

    // -------- epilogue: wave reduce -> LDS -> one global atomic/bin/block ----
    __shared__ float        redS[BINS];
    __shared__ unsigned int redC[BINS];
    if (tid < BINS) { redS[tid] = 0.0f; redC[tid] = 0u; }
    __syncthreads();

    const int lane = tid & 63;
#pragma unroll
    for (int b = 0; b < BINS; ++b) {
        float s = sb[b];
#pragma unroll
        for (int off = 32; off > 0; off >>= 1) s += __shfl_down(s, off);
        if (lane == 0) {
            atomicAdd(&redS[b], s);
            atomicAdd(&redC[b], cw[b]);   // cw is wave-uniform (ballot-derived)
        }
    }
    __syncthreads();
    if (tid < BINS) {
        atomicAdd(&gsum[tid], redS[tid]);
        atomicAdd(&gcnt[tid], redC[tid]);
    }
}

__global__ void ghm_finalize(const float* __restrict__ gsum,
                             const unsigned int* __restrict__ gcnt,
                             float* __restrict__ out)
{
    if (threadIdx.x == 0 && blockIdx.x == 0) {
        int n = 0;
#pragma unroll
        for (int b = 0; b < BINS; ++b) n += (gcnt[b] > 0u) ? 1 : 0;
        float nn = (float)(n > 0 ? n : 1);
        float acc = 0.0f;
#pragma unroll
        for (int b = 0; b < BINS; ++b) {
            if (gcnt[b] > 0u)
                acc += gsum[b] / ((float)gcnt[b] * nn);  // counts < 2^24: exact
        }
        out[0] = -0.6931471805599453f * acc;   // fold -ln(2) from log2 domain
    }
}

extern "C" void kernel_launch(void* const* d_in, const int* in_sizes, int n_in,
                              void* d_out, int out_size, void* d_ws, size_t ws_size,
                              hipStream_t stream)
{
    const float* p = (const float*)d_in[0];   // inputs (probabilities)
    const float* t = (const float*)d_in[1];   // targets (0/1 floats)
    const int n  = in_sizes[0];               // 262144*128
    const int n4 = n >> 2;                    // divisible by 4

    float*        gsum = (float*)d_ws;
    unsigned int* gcnt = (unsigned int*)((char*)d_ws + BINS * sizeof(float));

    // d_ws is re-poisoned to 0xAA before every timed launch — zero it (capturable)
    hipMemsetAsync(d_ws, 0, BINS * (sizeof(float) + sizeof(unsigned int)), stream);

    const int threads = 256;
    const int blocks  = 2048;   // 16 float4/thread -> ngrp = 4 (even, fully pipelined)
    ghm_partial<<<blocks, threads, 0, stream>>>(
        (const f4*)p, (const f4*)t, gsum, gcnt, n4);

    ghm_finalize<<<1, 64, 0, stream>>>(gsum, gcnt, (float*)d_out);
}